// Round 7
// baseline (69.151 us; speedup 1.0000x reference)
//
#include <hip/hip_runtime.h>
#include <hip/hip_bf16.h>
#include <stdint.h>

#define B_ 4
#define K_ 2048
#define D_ 512
#define H_ 8
#define ATTN_ 128
#define M_ (B_ * K_)   // 8192

typedef __attribute__((ext_vector_type(4))) float f32x4;
typedef __attribute__((ext_vector_type(8))) short bf16x8;
typedef __attribute__((ext_vector_type(8))) unsigned short u16x8;
typedef __attribute__((ext_vector_type(2))) unsigned int u32x2;

__device__ __forceinline__ unsigned short f2bf(float f) {
    union { float f; unsigned int i; } x; x.f = f;
    unsigned int r = x.i + 0x7fffu + ((x.i >> 16) & 1u);   // RNE
    return (unsigned short)(r >> 16);
}
__device__ __forceinline__ float bf2f(unsigned short u) {
    union { unsigned int i; float f; } x; x.i = ((unsigned int)u) << 16; return x.f;
}
__device__ __forceinline__ void gload_lds16(const unsigned short* g, unsigned short* l) {
    __builtin_amdgcn_global_load_lds(
        (const __attribute__((address_space(1))) void*)g,
        (__attribute__((address_space(3))) void*)l, 16, 0, 0);
}
__device__ __forceinline__ unsigned lds_addr(const void* p) {
    return (unsigned)(unsigned long long)
        (const __attribute__((address_space(3))) void*)p;
}

// ---------------------------------------------------------------------------
// fp32 -> bf16 conversion: weights only (4 tensors)
// ---------------------------------------------------------------------------
struct Cvt { const float* s; unsigned short* d; int n8; };
struct CvtA { Cvt c[4]; };

__global__ __launch_bounds__(256)
void cvt_multi(CvtA a) {
    const Cvt c = a.c[blockIdx.y];
    const float4* s4 = (const float4*)c.s;
    u16x8* d8 = (u16x8*)c.d;
    for (int g = blockIdx.x * 256 + threadIdx.x; g < c.n8; g += gridDim.x * 256) {
        float4 f0 = s4[2 * g], f1 = s4[2 * g + 1];
        u16x8 o;
        o[0] = f2bf(f0.x); o[1] = f2bf(f0.y); o[2] = f2bf(f0.z); o[3] = f2bf(f0.w);
        o[4] = f2bf(f1.x); o[5] = f2bf(f1.y); o[6] = f2bf(f1.z); o[7] = f2bf(f1.w);
        d8[g] = o;
    }
}

// ---------------------------------------------------------------------------
// Unified small-tile GEMM: C[8192,512] = A[8192,512] @ W[512,512]^T + bias.
// Tile 64x128, BK=32, 256 threads (4 waves, 2x2; wave tile 32x64 = the
// round-2-validated fragment layout). LDS 24 KB -> up to 6 blocks/CU
// co-resident; cross-block TLP hides load latency + barrier drains (the
// thing rounds 4-6 failed to get from intra-block scheduling at 1 block/CU).
// Swizzle (BK=32 superrow scheme): logical (row r, k-chunk ch of 8 elems)
// lives at LDS chunk (r>>1)*8 + slot, slot = ((r&1)*4+ch) ^ ((r>>1)&7).
// Balanced 2-way bank aliasing on ds_read_b128 (free per m136).
// A_FP32: A staged via reg (fp32->bf16 inline); else gload_lds direct.
// ---------------------------------------------------------------------------
struct GArgs {
    const void* A[3];
    const unsigned short* Wt[3];
    const float* bias[3];
    void* C[3];
};

template<bool A_FP32, bool OUT_BF16>
__global__ __launch_bounds__(256, 6)
void gemm64(GArgs args)
{
    __shared__ unsigned short As[2][64 * 32];    // 4 KB x2
    __shared__ unsigned short Bs[2][128 * 32];   // 8 KB x2

    const int z = blockIdx.y;
    const void* Az = args.A[z];
    const unsigned short* Wz = args.Wt[z];
    const float* biz = args.bias[z];
    void* Cz = args.C[z];

    const int id  = blockIdx.x;                  // 512 blocks: 128 m x 4 n
    const int swz = (id & 7) * 64 + (id >> 3);   // XCD-contiguous (512%8==0)
    const int bm  = (swz >> 2) * 64;
    const int bn  = (swz & 3) * 128;

    const int tid = threadIdx.x;
    const int w   = tid >> 6;                    // wave 0..3
    const int l   = tid & 63;
    const int lr  = l & 15;
    const int lhi = l >> 4;
    const int wm  = (w >> 1) * 32;               // 2x2 wave grid
    const int wn  = (w & 1) * 64;

    f32x4 acc[2][4];
    #pragma unroll
    for (int i = 0; i < 2; ++i)
        #pragma unroll
        for (int j = 0; j < 4; ++j) acc[i][j] = (f32x4){0.f, 0.f, 0.f, 0.f};

    // A: 256 chunks (64 rows x 4 k-chunks), 1 per thread.
    auto stageA = [&](int buf, int t) {
        const int k0 = t * 32;
        const int sr = tid >> 3, slot = tid & 7;
        const int val = slot ^ (sr & 7);
        const int r = sr * 2 + (val >> 2), ch = val & 3;
        if (A_FP32) {
            const float* src = (const float*)Az + (size_t)(bm + r) * D_ + k0 + ch * 8;
            float4 f0 = *(const float4*)src;
            float4 f1 = *(const float4*)(src + 4);
            u16x8 o;
            o[0] = f2bf(f0.x); o[1] = f2bf(f0.y); o[2] = f2bf(f0.z); o[3] = f2bf(f0.w);
            o[4] = f2bf(f1.x); o[5] = f2bf(f1.y); o[6] = f2bf(f1.z); o[7] = f2bf(f1.w);
            *(u16x8*)&As[buf][tid * 8] = o;                  // linear 16B/thread
        } else {
            gload_lds16((const unsigned short*)Az + (size_t)(bm + r) * D_ + k0 + ch * 8,
                        &As[buf][(w * 64) * 8]);             // wave-uniform base
        }
    };
    // B: 512 chunks (128 rows x 4 k-chunks), 2 per thread.
    auto stageB = [&](int buf, int t) {
        const int k0 = t * 32;
        #pragma unroll
        for (int it = 0; it < 2; ++it) {
            const int cid = it * 256 + tid;
            const int sr = cid >> 3, slot = cid & 7;
            const int val = slot ^ (sr & 7);
            const int r = sr * 2 + (val >> 2), ch = val & 3;
            gload_lds16(Wz + (size_t)(bn + r) * D_ + k0 + ch * 8,
                        &Bs[buf][(it * 256 + w * 64) * 8]);
        }
    };
    // logical (row, kchunk) -> LDS offset in shorts
    auto fragOff = [&](int row, int kchunk) {
        const int sr = row >> 1;
        const int slot = (((row & 1) << 2) + kchunk) ^ (sr & 7);
        return sr * 64 + slot * 8;
    };

    stageA(0, 0); stageB(0, 0);
    __syncthreads();

    int buf = 0;
    for (int t = 0; t < 16; ++t) {               // K = 512 = 16 x 32
        if (t < 15) { stageA(buf ^ 1, t + 1); stageB(buf ^ 1, t + 1); }
        bf16x8 af[2], bfr[4];
        #pragma unroll
        for (int fm = 0; fm < 2; ++fm)
            af[fm] = *(const bf16x8*)&As[buf][fragOff(wm + fm * 16 + lr, lhi)];
        #pragma unroll
        for (int fn = 0; fn < 4; ++fn)
            bfr[fn] = *(const bf16x8*)&Bs[buf][fragOff(wn + fn * 16 + lr, lhi)];
        #pragma unroll
        for (int fm = 0; fm < 2; ++fm)
            #pragma unroll
            for (int fn = 0; fn < 4; ++fn)
                acc[fm][fn] = __builtin_amdgcn_mfma_f32_16x16x32_bf16(
                    af[fm], bfr[fn], acc[fm][fn], 0, 0, 0);
        __syncthreads();                         // drains gload_lds + ds ops
        buf ^= 1;
    }

    float bv[4];
    #pragma unroll
    for (int fn = 0; fn < 4; ++fn) bv[fn] = biz[bn + wn + fn * 16 + lr];

    #pragma unroll
    for (int fm = 0; fm < 2; ++fm)
        #pragma unroll
        for (int fn = 0; fn < 4; ++fn)
            #pragma unroll
            for (int rr = 0; rr < 4; ++rr) {
                const int row = bm + wm + fm * 16 + lhi * 4 + rr;  // C/D layout
                const int col = bn + wn + fn * 16 + lr;
                const float val = acc[fm][fn][rr] + bv[fn];
                if (OUT_BF16)
                    ((unsigned short*)Cz)[(size_t)row * 512 + col] = f2bf(val);
                else
                    ((float*)Cz)[(size_t)row * 512 + col] = val;
            }
}

// ---------------------------------------------------------------------------
// MFMA banded-causal local attention (round-3 validated, unchanged).
// ---------------------------------------------------------------------------
__global__ __launch_bounds__(256)
void attn_mfma(const unsigned short* __restrict__ qb,
               const unsigned short* __restrict__ kb,
               const unsigned short* __restrict__ vb,
               unsigned short* __restrict__ ob)
{
    __shared__ unsigned short Ksh[192 * 64];
    __shared__ unsigned short Vsh[4 * 192 * 16];
    __shared__ unsigned short Psh[4 * 16 * 200];

    const int flat = blockIdx.x + 32 * (blockIdx.y + 8 * blockIdx.z);
    const int lg   = (flat & 7) * 128 + (flat >> 3);
    const int tile = lg & 31;
    const int h    = (lg >> 5) & 7;
    const int b    = lg >> 8;

    const int i0 = tile * 64;
    const int j0 = i0 - 128;
    const int tid = threadIdx.x;
    const int w   = tid >> 6;
    const int l   = tid & 63;
    const int lr  = l & 15;
    const int lhi = l >> 4;
    const float scale = 0.0220970869120796f;

    const size_t hbase = ((size_t)b * K_) * 512 + (size_t)h * 64;
    const unsigned short* kh = kb + hbase;
    const unsigned short* vh = vb + hbase;
    const unsigned short* qh = qb + hbase;
    unsigned short* oh = ob + hbase;

    #pragma unroll
    for (int it = 0; it < 6; ++it) {
        const int cg  = it * 4 + w;
        const int cid = cg * 64 + l;
        const int r = cid >> 3, c = cid & 7;
        const int cs = c ^ (r & 7);
        int j = j0 + r; if (j < 0) j = 0;
        gload_lds16(kh + (size_t)j * 512 + cs * 8, &Ksh[cg * 64 * 8]);
    }
    #pragma unroll
    for (int it = 0; it < 6; ++it) {
        const int cg  = it * 4 + w;
        const int cid = cg * 64 + l;
        const int blk = cid / 384;
        const int rem = cid - blk * 384;
        const int prow = rem >> 1, hf = rem & 1;
        const int a = prow >> 2, bb = prow & 3;
        const int k = (a < 24) ? (8 * a + bb) : (8 * (a - 24) + 4 + bb);
        int j = j0 + k; if (j < 0) j = 0;
        gload_lds16(vh + (size_t)j * 512 + blk * 16 + hf * 8, &Vsh[cg * 64 * 8]);
    }

    bf16x8 qa[2];
    {
        const unsigned short* qrow = qh + (size_t)(i0 + 16 * w + lr) * 512;
        qa[0] = *(const bf16x8*)(qrow + lhi * 8);
        qa[1] = *(const bf16x8*)(qrow + 32 + lhi * 8);
    }
    __syncthreads();

    const int jcbase = w & ~1;
    f32x4 sacc[10];
    #pragma unroll
    for (int jc = 0; jc < 10; ++jc) sacc[jc] = (f32x4){0.f, 0.f, 0.f, 0.f};

    __builtin_amdgcn_s_setprio(1);
    #pragma unroll
    for (int kk = 0; kk < 2; ++kk) {
        const int ch = (kk * 4 + lhi) ^ (lr & 7);
        #pragma unroll
        for (int jc = 0; jc < 10; ++jc) {
            const int row = (jcbase + jc) * 16 + lr;
            bf16x8 kf = *(const bf16x8*)&Ksh[row * 64 + ch * 8];
            sacc[jc] = __builtin_amdgcn_mfma_f32_16x16x32_bf16(
                qa[kk], kf, sacc[jc], 0, 0, 0);
        }
    }
    __builtin_amdgcn_s_setprio(0);

    unsigned short* myP = &Psh[w * 3200];
    const int lo0 = 128 - i0;
    float lsum[4] = {0.f, 0.f, 0.f, 0.f};
    #pragma unroll
    for (int jc = 0; jc < 10; ++jc) {
        const int jcol = (jcbase + jc) * 16 + lr;
        #pragma unroll
        for (int rr = 0; rr < 4; ++rr) {
            const int iloc = 16 * w + 4 * lhi + rr;
            const bool ok = (jcol >= iloc) && (jcol <= iloc + ATTN_) && (jcol >= lo0);
            const float p = ok ? __expf(fminf(sacc[jc][rr] * scale, 80.f)) : 0.f;
            lsum[rr] += p;
            myP[(4 * lhi + rr) * 200 + jcol] = f2bf(p);
        }
    }
    #pragma unroll
    for (int rr = 0; rr < 4; ++rr) {
        float s = lsum[rr];
        s += __shfl_xor(s, 1, 16);
        s += __shfl_xor(s, 2, 16);
        s += __shfl_xor(s, 4, 16);
        s += __shfl_xor(s, 8, 16);
        lsum[rr] = s;
    }

    const int kcbase = w >> 1;
    f32x4 oacc[4];
    #pragma unroll
    for (int fn = 0; fn < 4; ++fn) oacc[fn] = (f32x4){0.f, 0.f, 0.f, 0.f};
    const unsigned vbase = lds_addr(&Vsh[0]) + (unsigned)(l * 8);

    for (int kc5 = 0; kc5 < 5; ++kc5) {
        const int kc = kcbase + kc5;
        bf16x8 pa = *(const bf16x8*)&myP[lr * 200 + kc * 32 + lhi * 8];
        u32x2 vlo[4], vhi[4];
        #pragma unroll
        for (int fn = 0; fn < 4; ++fn) {
            const unsigned addr = vbase + (unsigned)((fn * 3072 + kc * 256) * 2);
            asm volatile("ds_read_b64_tr_b16 %0, %1" : "=v"(vlo[fn]) : "v"(addr));
            asm volatile("ds_read_b64_tr_b16 %0, %1 offset:3072"
                         : "=v"(vhi[fn]) : "v"(addr));
        }
        asm volatile("s_waitcnt lgkmcnt(0)" ::: "memory");
        __builtin_amdgcn_sched_barrier(0);
        __builtin_amdgcn_s_setprio(1);
        #pragma unroll
        for (int fn = 0; fn < 4; ++fn) {
            union { u32x2 h[2]; bf16x8 v; } u;
            u.h[0] = vlo[fn]; u.h[1] = vhi[fn];
            oacc[fn] = __builtin_amdgcn_mfma_f32_16x16x32_bf16(
                pa, u.v, oacc[fn], 0, 0, 0);
        }
        __builtin_amdgcn_s_setprio(0);
    }

    float inv[4];
    #pragma unroll
    for (int rr = 0; rr < 4; ++rr) inv[rr] = 1.f / lsum[rr];
    #pragma unroll
    for (int fn = 0; fn < 4; ++fn)
        #pragma unroll
        for (int rr = 0; rr < 4; ++rr) {
            const int row = i0 + 16 * w + 4 * lhi + rr;
            oh[(size_t)row * 512 + fn * 16 + lr] = f2bf(oacc[fn][rr] * inv[rr]);
        }
}

// ---------------------------------------------------------------------------
extern "C" void kernel_launch(void* const* d_in, const int* in_sizes, int n_in,
                              void* d_out, int out_size, void* d_ws, size_t ws_size,
                              hipStream_t stream)
{
    const float* query = (const float*)d_in[0];
    const float* key   = (const float*)d_in[1];
    const float* value = (const float*)d_in[2];
    const float* W_q   = (const float*)d_in[3];
    const float* b_q   = (const float*)d_in[4];
    const float* W_k   = (const float*)d_in[5];
    const float* b_k   = (const float*)d_in[6];
    const float* W_v   = (const float*)d_in[7];
    const float* b_v   = (const float*)d_in[8];
    const float* W_o   = (const float*)d_in[9];
    const float* b_o   = (const float*)d_in[10];
    float* out = (float*)d_out;

    const size_t NX = (size_t)M_ * 512;
    const size_t NW = 512 * 512;
    unsigned short* wqb = (unsigned short*)d_ws;
    unsigned short* wkb = wqb + NW;
    unsigned short* wvb = wkb + NW;
    unsigned short* wob = wvb + NW;
    unsigned short* qp  = wob + NW;
    unsigned short* kp  = qp + NX;
    unsigned short* vp  = kp + NX;
    unsigned short* ap  = vp + NX;

    const int NW8 = (int)(NW / 8);

    CvtA a;
    a.c[0] = { W_q, wqb, NW8 };
    a.c[1] = { W_k, wkb, NW8 };
    a.c[2] = { W_v, wvb, NW8 };
    a.c[3] = { W_o, wob, NW8 };
    cvt_multi<<<dim3(32, 4), 256, 0, stream>>>(a);

    GArgs qa;
    qa.A[0] = query; qa.A[1] = key; qa.A[2] = value;
    qa.Wt[0] = wqb;  qa.Wt[1] = wkb; qa.Wt[2] = wvb;
    qa.bias[0] = b_q; qa.bias[1] = b_k; qa.bias[2] = b_v;
    qa.C[0] = qp; qa.C[1] = kp; qa.C[2] = vp;
    gemm64<true, true><<<dim3(512, 3), 256, 0, stream>>>(qa);

    attn_mfma<<<dim3(32, 8, 4), 256, 0, stream>>>(qp, kp, vp, ap);

    GArgs oa;
    oa.A[0] = ap; oa.A[1] = nullptr; oa.A[2] = nullptr;
    oa.Wt[0] = wob; oa.Wt[1] = nullptr; oa.Wt[2] = nullptr;
    oa.bias[0] = b_o; oa.bias[1] = nullptr; oa.bias[2] = nullptr;
    oa.C[0] = out; oa.C[1] = nullptr; oa.C[2] = nullptr;
    gemm64<false, false><<<dim3(512, 1), 256, 0, stream>>>(oa);
}

// Round 8
// 61.047 us; speedup vs baseline: 1.1328x; 1.1328x over previous
//
#include <hip/hip_runtime.h>
#include <hip/hip_bf16.h>
#include <stdint.h>

#define B_ 4
#define K_ 2048
#define D_ 512
#define H_ 8
#define ATTN_ 128
#define M_ (B_ * K_)   // 8192

typedef __attribute__((ext_vector_type(4))) float f32x4;
typedef __attribute__((ext_vector_type(8))) short bf16x8;
typedef __attribute__((ext_vector_type(8))) unsigned short u16x8;
typedef __attribute__((ext_vector_type(2))) unsigned int u32x2;

__device__ __forceinline__ unsigned short f2bf(float f) {
    union { float f; unsigned int i; } x; x.f = f;
    unsigned int r = x.i + 0x7fffu + ((x.i >> 16) & 1u);   // RNE
    return (unsigned short)(r >> 16);
}
__device__ __forceinline__ float bf2f(unsigned short u) {
    union { unsigned int i; float f; } x; x.i = ((unsigned int)u) << 16; return x.f;
}
__device__ __forceinline__ void gload_lds16(const unsigned short* g, unsigned short* l) {
    __builtin_amdgcn_global_load_lds(
        (const __attribute__((address_space(1))) void*)g,
        (__attribute__((address_space(3))) void*)l, 16, 0, 0);
}
__device__ __forceinline__ unsigned lds_addr(const void* p) {
    return (unsigned)(unsigned long long)
        (const __attribute__((address_space(3))) void*)p;
}

// ---------------------------------------------------------------------------
// fp32 -> bf16 conversion: weights only (4 tensors)
// ---------------------------------------------------------------------------
struct Cvt { const float* s; unsigned short* d; int n8; };
struct CvtA { Cvt c[4]; };

__global__ __launch_bounds__(256)
void cvt_multi(CvtA a) {
    const Cvt c = a.c[blockIdx.y];
    const float4* s4 = (const float4*)c.s;
    u16x8* d8 = (u16x8*)c.d;
    for (int g = blockIdx.x * 256 + threadIdx.x; g < c.n8; g += gridDim.x * 256) {
        float4 f0 = s4[2 * g], f1 = s4[2 * g + 1];
        u16x8 o;
        o[0] = f2bf(f0.x); o[1] = f2bf(f0.y); o[2] = f2bf(f0.z); o[3] = f2bf(f0.w);
        o[4] = f2bf(f1.x); o[5] = f2bf(f1.y); o[6] = f2bf(f1.z); o[7] = f2bf(f1.w);
        d8[g] = o;
    }
}

// ---------------------------------------------------------------------------
// Tall-tile GEMM: C[8192,512] = A[8192,512] @ W[512,512]^T + bias.
// Tile 64(M) x 128(N), BK=64 -> only 8 K-steps. 256 threads (4 waves, 2x2;
// wave tile 32x64 = round-2-validated fragments & XOR swizzle, row stride 64).
// LDS 48 KB -> 3 blocks/CU co-resident (round 7 proved small-LDS co-residency;
// round 4 proved 64 KB gets 1 block/CU). Cross-block TLP hides load latency
// and barrier drains -- the thing intra-block scheduling (r5/r6) could not.
// XCD-local mapping: XCD x = id&7 owns m-tiles [16x,16x+16) for ALL 4 n-tiles
// -> per-XCD A working set 2 MB, L2-resident, kills the 4-way A re-fetch.
// A_FP32: A reg-staged with inline fp32->bf16 (T14 split); else gload_lds.
// ---------------------------------------------------------------------------
struct GArgs {
    const void* A[3];
    const unsigned short* Wt[3];
    const float* bias[3];
    void* C[3];
};

template<bool A_FP32, bool OUT_BF16>
__global__ __launch_bounds__(256, 3)
void gemm_tall(GArgs args)
{
    __shared__ unsigned short As[2][64 * 64];    // 8 KB x2
    __shared__ unsigned short Bs[2][128 * 64];   // 16 KB x2

    const int idf = blockIdx.x;
    const int z   = idf >> 9;                    // 512 blocks per z
    const int id  = idf & 511;
    const void* Az = args.A[z];
    const unsigned short* Wz = args.Wt[z];
    const float* biz = args.bias[z];
    void* Cz = args.C[z];

    // XCD x = id&7 (HW round-robin): m-tiles [16x, 16x+16), all 4 n-tiles
    const int x  = id & 7;
    const int i  = id >> 3;                      // 0..63
    const int bm = (x * 16 + (i >> 2)) * 64;
    const int bn = (i & 3) * 128;

    const int tid = threadIdx.x;
    const int w   = tid >> 6;                    // wave 0..3
    const int l   = tid & 63;
    const int lr  = l & 15;
    const int lhi = l >> 4;
    const int wm  = (w >> 1) * 32;               // 2x2 wave grid
    const int wn  = (w & 1) * 64;

    f32x4 acc[2][4];
    #pragma unroll
    for (int a = 0; a < 2; ++a)
        #pragma unroll
        for (int b = 0; b < 4; ++b) acc[a][b] = (f32x4){0.f, 0.f, 0.f, 0.f};

    float4 fa[2][2];   // in-flight A tile (fp32 path), static-indexed

    // A: 512 chunks (64 rows x 8 k-chunks of 8 bf16). fp32 path: 2/thread.
    auto loadA = [&](int t) {
        const int k0 = t * 64;
        #pragma unroll
        for (int it = 0; it < 2; ++it) {
            const int cid = it * 256 + tid;
            const int r = cid >> 3;
            const int c = (cid & 7) ^ (r & 7);   // load-side XOR permutation
            const float* src = (const float*)Az + (size_t)(bm + r) * D_ + k0 + c * 8;
            fa[it][0] = *(const float4*)src;
            fa[it][1] = *(const float4*)(src + 4);
        }
    };
    auto writeA = [&](int buf) {
        #pragma unroll
        for (int it = 0; it < 2; ++it) {
            const int cid = it * 256 + tid;
            u16x8 o;
            o[0] = f2bf(fa[it][0].x); o[1] = f2bf(fa[it][0].y);
            o[2] = f2bf(fa[it][0].z); o[3] = f2bf(fa[it][0].w);
            o[4] = f2bf(fa[it][1].x); o[5] = f2bf(fa[it][1].y);
            o[6] = f2bf(fa[it][1].z); o[7] = f2bf(fa[it][1].w);
            *(u16x8*)&As[buf][cid * 8] = o;      // linear dest: conflict-free
        }
    };
    auto stageA_bf16 = [&](int buf, int t) {     // bf16 path: 2 gload_lds/wave
        const int k0 = t * 64;
        #pragma unroll
        for (int it = 0; it < 2; ++it) {
            const int cg  = it * 4 + w;          // 8 chunk-groups of 64
            const int cid = cg * 64 + l;
            const int r = cid >> 3;
            const int c = (cid & 7) ^ (r & 7);
            gload_lds16((const unsigned short*)Az + (size_t)(bm + r) * D_ + k0 + c * 8,
                        &As[buf][cg * 512]);
        }
    };
    // B: 1024 chunks (128 rows x 8 k-chunks): 4 gload_lds per wave.
    auto stageB = [&](int buf, int t) {
        const int k0 = t * 64;
        #pragma unroll
        for (int it = 0; it < 4; ++it) {
            const int cg  = it * 4 + w;          // 16 chunk-groups of 64
            const int cid = cg * 64 + l;
            const int r = cid >> 3;
            const int c = (cid & 7) ^ (r & 7);
            gload_lds16(Wz + (size_t)(bn + r) * D_ + k0 + c * 8,
                        &Bs[buf][cg * 512]);
        }
    };

    // Prologue
    if (A_FP32) { loadA(0); writeA(0); }
    else        { stageA_bf16(0, 0); }
    stageB(0, 0);
    __syncthreads();

    int buf = 0;
    for (int t = 0; t < 8; ++t) {                // K = 512 = 8 x 64
        if (t < 7) {
            if (A_FP32) loadA(t + 1);            // issue early (T14 split)
            else        stageA_bf16(buf ^ 1, t + 1);
            stageB(buf ^ 1, t + 1);
        }
        #pragma unroll
        for (int kk = 0; kk < 2; ++kk) {
            bf16x8 af[2], bfr[4];
            #pragma unroll
            for (int fm = 0; fm < 2; ++fm) {
                const int row = wm + fm * 16 + lr;
                const int ch  = (kk * 4 + lhi) ^ (lr & 7);
                af[fm] = *(const bf16x8*)&As[buf][row * 64 + ch * 8];
            }
            #pragma unroll
            for (int fn = 0; fn < 4; ++fn) {
                const int row = wn + fn * 16 + lr;
                const int ch  = (kk * 4 + lhi) ^ (lr & 7);
                bfr[fn] = *(const bf16x8*)&Bs[buf][row * 64 + ch * 8];
            }
            #pragma unroll
            for (int fm = 0; fm < 2; ++fm)
                #pragma unroll
                for (int fn = 0; fn < 4; ++fn)
                    acc[fm][fn] = __builtin_amdgcn_mfma_f32_16x16x32_bf16(
                        af[fm], bfr[fn], acc[fm][fn], 0, 0, 0);
        }
        if (A_FP32 && t < 7) writeA(buf ^ 1);    // cvt+write late
        __syncthreads();
        buf ^= 1;
    }

    float bv[4];
    #pragma unroll
    for (int fn = 0; fn < 4; ++fn) bv[fn] = biz[bn + wn + fn * 16 + lr];

    #pragma unroll
    for (int fm = 0; fm < 2; ++fm)
        #pragma unroll
        for (int fn = 0; fn < 4; ++fn)
            #pragma unroll
            for (int rr = 0; rr < 4; ++rr) {
                const int row = bm + wm + fm * 16 + lhi * 4 + rr;
                const int col = bn + wn + fn * 16 + lr;
                const float val = acc[fm][fn][rr] + bv[fn];
                if (OUT_BF16)
                    ((unsigned short*)Cz)[(size_t)row * 512 + col] = f2bf(val);
                else
                    ((float*)Cz)[(size_t)row * 512 + col] = val;
            }
}

// ---------------------------------------------------------------------------
// MFMA banded-causal local attention (round-3 validated, unchanged).
// ---------------------------------------------------------------------------
__global__ __launch_bounds__(256)
void attn_mfma(const unsigned short* __restrict__ qb,
               const unsigned short* __restrict__ kb,
               const unsigned short* __restrict__ vb,
               unsigned short* __restrict__ ob)
{
    __shared__ unsigned short Ksh[192 * 64];
    __shared__ unsigned short Vsh[4 * 192 * 16];
    __shared__ unsigned short Psh[4 * 16 * 200];

    const int flat = blockIdx.x + 32 * (blockIdx.y + 8 * blockIdx.z);
    const int lg   = (flat & 7) * 128 + (flat >> 3);
    const int tile = lg & 31;
    const int h    = (lg >> 5) & 7;
    const int b    = lg >> 8;

    const int i0 = tile * 64;
    const int j0 = i0 - 128;
    const int tid = threadIdx.x;
    const int w   = tid >> 6;
    const int l   = tid & 63;
    const int lr  = l & 15;
    const int lhi = l >> 4;
    const float scale = 0.0220970869120796f;

    const size_t hbase = ((size_t)b * K_) * 512 + (size_t)h * 64;
    const unsigned short* kh = kb + hbase;
    const unsigned short* vh = vb + hbase;
    const unsigned short* qh = qb + hbase;
    unsigned short* oh = ob + hbase;

    #pragma unroll
    for (int it = 0; it < 6; ++it) {
        const int cg  = it * 4 + w;
        const int cid = cg * 64 + l;
        const int r = cid >> 3, c = cid & 7;
        const int cs = c ^ (r & 7);
        int j = j0 + r; if (j < 0) j = 0;
        gload_lds16(kh + (size_t)j * 512 + cs * 8, &Ksh[cg * 64 * 8]);
    }
    #pragma unroll
    for (int it = 0; it < 6; ++it) {
        const int cg  = it * 4 + w;
        const int cid = cg * 64 + l;
        const int blk = cid / 384;
        const int rem = cid - blk * 384;
        const int prow = rem >> 1, hf = rem & 1;
        const int a = prow >> 2, bb = prow & 3;
        const int k = (a < 24) ? (8 * a + bb) : (8 * (a - 24) + 4 + bb);
        int j = j0 + k; if (j < 0) j = 0;
        gload_lds16(vh + (size_t)j * 512 + blk * 16 + hf * 8, &Vsh[cg * 64 * 8]);
    }

    bf16x8 qa[2];
    {
        const unsigned short* qrow = qh + (size_t)(i0 + 16 * w + lr) * 512;
        qa[0] = *(const bf16x8*)(qrow + lhi * 8);
        qa[1] = *(const bf16x8*)(qrow + 32 + lhi * 8);
    }
    __syncthreads();

    const int jcbase = w & ~1;
    f32x4 sacc[10];
    #pragma unroll
    for (int jc = 0; jc < 10; ++jc) sacc[jc] = (f32x4){0.f, 0.f, 0.f, 0.f};

    __builtin_amdgcn_s_setprio(1);
    #pragma unroll
    for (int kk = 0; kk < 2; ++kk) {
        const int ch = (kk * 4 + lhi) ^ (lr & 7);
        #pragma unroll
        for (int jc = 0; jc < 10; ++jc) {
            const int row = (jcbase + jc) * 16 + lr;
            bf16x8 kf = *(const bf16x8*)&Ksh[row * 64 + ch * 8];
            sacc[jc] = __builtin_amdgcn_mfma_f32_16x16x32_bf16(
                qa[kk], kf, sacc[jc], 0, 0, 0);
        }
    }
    __builtin_amdgcn_s_setprio(0);

    unsigned short* myP = &Psh[w * 3200];
    const int lo0 = 128 - i0;
    float lsum[4] = {0.f, 0.f, 0.f, 0.f};
    #pragma unroll
    for (int jc = 0; jc < 10; ++jc) {
        const int jcol = (jcbase + jc) * 16 + lr;
        #pragma unroll
        for (int rr = 0; rr < 4; ++rr) {
            const int iloc = 16 * w + 4 * lhi + rr;
            const bool ok = (jcol >= iloc) && (jcol <= iloc + ATTN_) && (jcol >= lo0);
            const float p = ok ? __expf(fminf(sacc[jc][rr] * scale, 80.f)) : 0.f;
            lsum[rr] += p;
            myP[(4 * lhi + rr) * 200 + jcol] = f2bf(p);
        }
    }
    #pragma unroll
    for (int rr = 0; rr < 4; ++rr) {
        float s = lsum[rr];
        s += __shfl_xor(s, 1, 16);
        s += __shfl_xor(s, 2, 16);
        s += __shfl_xor(s, 4, 16);
        s += __shfl_xor(s, 8, 16);
        lsum[rr] = s;
    }

    const int kcbase = w >> 1;
    f32x4 oacc[4];
    #pragma unroll
    for (int fn = 0; fn < 4; ++fn) oacc[fn] = (f32x4){0.f, 0.f, 0.f, 0.f};
    const unsigned vbase = lds_addr(&Vsh[0]) + (unsigned)(l * 8);

    for (int kc5 = 0; kc5 < 5; ++kc5) {
        const int kc = kcbase + kc5;
        bf16x8 pa = *(const bf16x8*)&myP[lr * 200 + kc * 32 + lhi * 8];
        u32x2 vlo[4], vhi[4];
        #pragma unroll
        for (int fn = 0; fn < 4; ++fn) {
            const unsigned addr = vbase + (unsigned)((fn * 3072 + kc * 256) * 2);
            asm volatile("ds_read_b64_tr_b16 %0, %1" : "=v"(vlo[fn]) : "v"(addr));
            asm volatile("ds_read_b64_tr_b16 %0, %1 offset:3072"
                         : "=v"(vhi[fn]) : "v"(addr));
        }
        asm volatile("s_waitcnt lgkmcnt(0)" ::: "memory");
        __builtin_amdgcn_sched_barrier(0);
        __builtin_amdgcn_s_setprio(1);
        #pragma unroll
        for (int fn = 0; fn < 4; ++fn) {
            union { u32x2 h[2]; bf16x8 v; } u;
            u.h[0] = vlo[fn]; u.h[1] = vhi[fn];
            oacc[fn] = __builtin_amdgcn_mfma_f32_16x16x32_bf16(
                pa, u.v, oacc[fn], 0, 0, 0);
        }
        __builtin_amdgcn_s_setprio(0);
    }

    float inv[4];
    #pragma unroll
    for (int rr = 0; rr < 4; ++rr) inv[rr] = 1.f / lsum[rr];
    #pragma unroll
    for (int fn = 0; fn < 4; ++fn)
        #pragma unroll
        for (int rr = 0; rr < 4; ++rr) {
            const int row = i0 + 16 * w + 4 * lhi + rr;
            oh[(size_t)row * 512 + fn * 16 + lr] = f2bf(oacc[fn][rr] * inv[rr]);
        }
}

// ---------------------------------------------------------------------------
extern "C" void kernel_launch(void* const* d_in, const int* in_sizes, int n_in,
                              void* d_out, int out_size, void* d_ws, size_t ws_size,
                              hipStream_t stream)
{
    const float* query = (const float*)d_in[0];
    const float* key   = (const float*)d_in[1];
    const float* value = (const float*)d_in[2];
    const float* W_q   = (const float*)d_in[3];
    const float* b_q   = (const float*)d_in[4];
    const float* W_k   = (const float*)d_in[5];
    const float* b_k   = (const float*)d_in[6];
    const float* W_v   = (const float*)d_in[7];
    const float* b_v   = (const float*)d_in[8];
    const float* W_o   = (const float*)d_in[9];
    const float* b_o   = (const float*)d_in[10];
    float* out = (float*)d_out;

    const size_t NX = (size_t)M_ * 512;
    const size_t NW = 512 * 512;
    unsigned short* wqb = (unsigned short*)d_ws;
    unsigned short* wkb = wqb + NW;
    unsigned short* wvb = wkb + NW;
    unsigned short* wob = wvb + NW;
    unsigned short* qp  = wob + NW;
    unsigned short* kp  = qp + NX;
    unsigned short* vp  = kp + NX;
    unsigned short* ap  = vp + NX;

    const int NW8 = (int)(NW / 8);

    CvtA a;
    a.c[0] = { W_q, wqb, NW8 };
    a.c[1] = { W_k, wkb, NW8 };
    a.c[2] = { W_v, wvb, NW8 };
    a.c[3] = { W_o, wob, NW8 };
    cvt_multi<<<dim3(32, 4), 256, 0, stream>>>(a);

    GArgs qa;
    qa.A[0] = query; qa.A[1] = key; qa.A[2] = value;
    qa.Wt[0] = wqb;  qa.Wt[1] = wkb; qa.Wt[2] = wvb;
    qa.bias[0] = b_q; qa.bias[1] = b_k; qa.bias[2] = b_v;
    qa.C[0] = qp; qa.C[1] = kp; qa.C[2] = vp;
    gemm_tall<true, true><<<1536, 256, 0, stream>>>(qa);

    attn_mfma<<<dim3(32, 8, 4), 256, 0, stream>>>(qp, kp, vp, ap);

    GArgs oa;
    oa.A[0] = ap; oa.A[1] = nullptr; oa.A[2] = nullptr;
    oa.Wt[0] = wob; oa.Wt[1] = nullptr; oa.Wt[2] = nullptr;
    oa.bias[0] = b_o; oa.bias[1] = nullptr; oa.bias[2] = nullptr;
    oa.C[0] = out; oa.C[1] = nullptr; oa.C[2] = nullptr;
    gemm_tall<false, false><<<512, 256, 0, stream>>>(oa);
}